// Round 5
// baseline (615.481 us; speedup 1.0000x reference)
//
#include <hip/hip_runtime.h>
#include <cstdint>
#include <cstddef>

// out[m,n] = scale[m]*wscale[n]*(sum_k q[m,k]*w8[n,k] - azp[m]*azp_adj[n]) + bias[n]
// M=8192, K=4096, N=4096. Exact int8 path.

#define M_DIM 8192
#define K_DIM 4096
#define N_DIM 4096
#define NT 64   // K tiles of BK=64

typedef int v4i __attribute__((ext_vector_type(4)));

// ---------------------------------------------------------------------------
// Kernel 1 (fused): blocks [0, M) do per-token quant; blocks [M, M+N) do
// weight prep. Bit-identical math to the verified standalone kernels.
// ---------------------------------------------------------------------------
__global__ __launch_bounds__(256) void prep_kernel(
    const float* __restrict__ x, signed char* __restrict__ q,
    float* __restrict__ scale_out, int* __restrict__ azp_out,
    const int* __restrict__ w, signed char* __restrict__ w8,
    int* __restrict__ azp_adj)
{
    const int t = threadIdx.x;
    if (blockIdx.x < M_DIM) {
        // ---- per-token asymmetric quantization, one block per row ----
        const int m = blockIdx.x;
        const float4* row4 = (const float4*)(x + (size_t)m * K_DIM);

        float4 v[4];
        float mx = -3.4e38f, mn = 3.4e38f;
#pragma unroll
        for (int i = 0; i < 4; ++i) {
            v[i] = row4[i * 256 + t];                  // coalesced
            mx = fmaxf(mx, fmaxf(fmaxf(v[i].x, v[i].y), fmaxf(v[i].z, v[i].w)));
            mn = fminf(mn, fminf(fminf(v[i].x, v[i].y), fminf(v[i].z, v[i].w)));
        }
#pragma unroll
        for (int off = 32; off; off >>= 1) {
            mx = fmaxf(mx, __shfl_down(mx, off));
            mn = fminf(mn, __shfl_down(mn, off));
        }
        __shared__ float smx[4], smn[4];
        if ((t & 63) == 0) { smx[t >> 6] = mx; smn[t >> 6] = mn; }
        __syncthreads();
        mx = fmaxf(fmaxf(smx[0], smx[1]), fmaxf(smx[2], smx[3]));
        mn = fminf(fminf(smn[0], smn[1]), fminf(smn[2], smn[3]));

        const float scale = (mx - mn) / 255.0f;
        const int azp = (int)rintf(-128.0f - mn / scale);
        if (t == 0) { scale_out[m] = scale; azp_out[m] = azp; }

        int* qrow = (int*)(q + (size_t)m * K_DIM);
        const float* vf = (const float*)v;
#pragma unroll
        for (int i = 0; i < 4; ++i) {
            int b[4];
#pragma unroll
            for (int j = 0; j < 4; ++j) {
                int qv = (int)rintf(vf[4 * i + j] / scale) + azp;
                qv = qv < -128 ? -128 : (qv > 127 ? 127 : qv);
                b[j] = qv;
            }
            qrow[i * 256 + t] =
                (b[0] & 255) | ((b[1] & 255) << 8) | ((b[2] & 255) << 16) | ((b[3] & 255) << 24);
        }
    } else {
        // ---- weight prep: int32 [N,K] -> int8 [N,K] + column sums ----
        const int n = blockIdx.x - M_DIM;
        const int4* row = (const int4*)(w + (size_t)n * K_DIM);
        int* w8row = (int*)(w8 + (size_t)n * K_DIM);
        int sum = 0;
#pragma unroll
        for (int i = 0; i < 4; ++i) {
            int4 a = row[i * 256 + t];                 // coalesced
            sum += a.x + a.y + a.z + a.w;
            w8row[i * 256 + t] =
                (a.x & 255) | ((a.y & 255) << 8) | ((a.z & 255) << 16) | ((a.w & 255) << 24);
        }
#pragma unroll
        for (int off = 32; off; off >>= 1) sum += __shfl_down(sum, off);
        __shared__ int ssum[4];
        if ((t & 63) == 0) ssum[t >> 6] = sum;
        __syncthreads();
        if (t == 0) azp_adj[n] = ssum[0] + ssum[1] + ssum[2] + ssum[3];
    }
}

// ---------------------------------------------------------------------------
// Kernel 2: int8 GEMM, 256x256 block tile, BK=64, 8 waves (2M x 4N),
// per-wave 128x64 via mfma_i32_16x16x64_i8 -- NO LDS, NO BARRIERS.
//
// Round-5 theory: rounds 1/2/4 all landed at ~3060 cy/tile because the
// CU-wide ds_read burst (96 b128 ~1150 cy) is fair-interleaved by the LDS
// arbiter, so every wave's lgkmcnt completes at burst-end and tile time =
// LDS_total + MFMA_total (serial). The MFMA fragment layout for
// mfma_i32_16x16x64_i8 -- lane l: row base+(l&15), bytes (l>>4)*16.. -- is
// itself a coalesced GLOBAL pattern (16 rows x 64B = one dwordx4/frag), so
// fragments load direct global->VGPR. LDS existed only to dedup reads (A 4x,
// B 2x); per block-tile the unique set is 32 KB (~L1), strips are
// L2-resident (A-strip shared by 8 blocks, B by 4 within an XCD rectangle).
// Worst case zero-L1-hit -> L2-BW-settle ~1800 cy/tile (~97 us), best
// ~1350 (~75 us); both well under the measured 3060.
//
// Schedule per tile (dependency-driven, compiler-inserted counted vmcnt):
//   issue ah(kt) (4 loads); issue af/bf(kt+1) (8 loads, double-buffered
//   P/Q sets); 16 MFMA(af x bf); 16 MFMA(ah x bf). No sync instructions.
// Regs: acc 128 (AGPR) + cur 32 + next 32 + ah 16 + addr/misc ~30 ≈ 238
// unified -> 2 waves/SIMD at __launch_bounds__(512,2), no spill expected
// (verify: WRITE_SIZE stays ~134 MB).
//
// XCD rectangle map: dispatch i -> XCD i%8 (round-robin). Map (r=i&7,
// s=(i>>3)&31, rnd=i>>8) -> m_blk=16*rnd+4*(r>>1)+(s>>3), n_blk=8*(r&1)+
// (s&7): each XCD's 32 resident blocks form a 4m x 8n rectangle -> per
// K-tile touches 4+8 strip-slices = 192 KB, L2-resident. Bijective: 
// (r,s,rnd) recoverable from (m_blk,n_blk).
// ---------------------------------------------------------------------------
template<int RO>
__device__ __forceinline__ void mfma16(const v4i (&x)[4], const v4i (&y)[4], v4i (&acc)[8][4]) {
#pragma unroll
    for (int i = 0; i < 4; ++i)
#pragma unroll
        for (int j = 0; j < 4; ++j)
            acc[RO + i][j] = __builtin_amdgcn_mfma_i32_16x16x64_i8(x[i], y[j], acc[RO + i][j], 0, 0, 0);
}

__device__ __forceinline__ v4i ldg16(const signed char* p) {
    return *(const v4i*)p;
}

__global__ __launch_bounds__(512, 2) void gemm_kernel(
    const signed char* __restrict__ A,   // [M,K] quantized activations
    const signed char* __restrict__ B,   // [N,K] int8 weights
    const float* __restrict__ scale, const int* __restrict__ azp,
    const int* __restrict__ azp_adj, const float* __restrict__ wscale,
    const float* __restrict__ bias, float* __restrict__ out)
{
    const int t = threadIdx.x;
    const int lane = t & 63;
    const int wave = t >> 6;
    const int quad = lane >> 4;
    const int r16 = lane & 15;

    // XCD rectangle swizzle (see header comment)
    const int i = blockIdx.y * gridDim.x + blockIdx.x;    // 0..511
    const int r = i & 7, s = (i >> 3) & 31, rnd = i >> 8;
    const int bm = (16 * rnd + 4 * (r >> 1) + (s >> 3)) << 8;
    const int bn = (8 * (r & 1) + (s & 7)) << 8;

    const int wm = (wave >> 2) << 7;       // 0 or 128
    const int wn = (wave & 3) << 6;        // 0,64,128,192

    v4i acc[8][4];
#pragma unroll
    for (int ii = 0; ii < 8; ++ii)
#pragma unroll
        for (int j = 0; j < 4; ++j) acc[ii][j] = (v4i){0, 0, 0, 0};

    // fragment base addresses: lane supplies row base+r16, bytes quad*16..
    // frag f at +f*16 rows (= +f*65536 B); ah half at +64 rows (+262144 B);
    // K-tile kt at +kt*64 B.
    const signed char* aBase = A + (size_t)(bm + wm + r16) * K_DIM + quad * 16;
    const signed char* bBase = B + (size_t)(bn + wn + r16) * K_DIM + quad * 16;

    v4i afP[4], bfP[4], afQ[4], bfQ[4], ah[4];

    // prologue: tile 0 af/bf into set P
#pragma unroll
    for (int f = 0; f < 4; ++f) {
        afP[f] = ldg16(aBase + f * 65536);
        bfP[f] = ldg16(bBase + f * 65536);
    }

    for (int kt = 0; kt < NT; kt += 2) {
        const int k0 = kt << 6;
        // ---- tile kt (set P) ----
#pragma unroll
        for (int f = 0; f < 4; ++f)
            ah[f] = ldg16(aBase + 262144 + f * 65536 + k0);
#pragma unroll
        for (int f = 0; f < 4; ++f) {
            afQ[f] = ldg16(aBase + f * 65536 + k0 + 64);
            bfQ[f] = ldg16(bBase + f * 65536 + k0 + 64);
        }
        mfma16<0>(afP, bfP, acc);
        mfma16<4>(ah, bfP, acc);

        // ---- tile kt+1 (set Q) ----
#pragma unroll
        for (int f = 0; f < 4; ++f)
            ah[f] = ldg16(aBase + 262144 + f * 65536 + k0 + 64);
        if (kt + 2 < NT) {
#pragma unroll
            for (int f = 0; f < 4; ++f) {
                afP[f] = ldg16(aBase + f * 65536 + k0 + 128);
                bfP[f] = ldg16(bBase + f * 65536 + k0 + 128);
            }
        }
        mfma16<0>(afQ, bfQ, acc);
        mfma16<4>(ah, bfQ, acc);
    }

    // epilogue: out = scale[m]*wscale[n]*(acc - azp[m]*adj[n]) + bias[n]
#pragma unroll
    for (int ii = 0; ii < 8; ++ii) {
        const int mbase = bm + wm + ii * 16 + quad * 4;
        float sm[4]; int am[4];
#pragma unroll
        for (int rr = 0; rr < 4; ++rr) { sm[rr] = scale[mbase + rr]; am[rr] = azp[mbase + rr]; }
#pragma unroll
        for (int j = 0; j < 4; ++j) {
            const int n = bn + wn + j * 16 + r16;
            const float wsn = wscale[n];
            const int adjn = azp_adj[n];
            const float bn_ = bias[n];
#pragma unroll
            for (int rr = 0; rr < 4; ++rr) {
                const int c = acc[ii][j][rr] - am[rr] * adjn;
                out[(size_t)(mbase + rr) * N_DIM + n] = sm[rr] * wsn * (float)c + bn_;
            }
        }
    }
}

// ---------------------------------------------------------------------------
extern "C" void kernel_launch(void* const* d_in, const int* in_sizes, int n_in,
                              void* d_out, int out_size, void* d_ws, size_t ws_size,
                              hipStream_t stream) {
    const float* x      = (const float*)d_in[0];
    const int*   w      = (const int*)d_in[1];
    const float* wscale = (const float*)d_in[2];
    const float* bias   = (const float*)d_in[3];
    float* out = (float*)d_out;

    char* ws = (char*)d_ws;
    signed char* q8  = (signed char*)ws;                         // 32 MiB
    signed char* w8  = (signed char*)(ws + 33554432);            // 16 MiB
    float* scl       = (float*)(ws + 50331648);                  // 32 KiB
    int*   azp       = (int*)(ws + 50331648 + 32768);            // 32 KiB
    int*   adj       = (int*)(ws + 50331648 + 65536);            // 16 KiB

    prep_kernel<<<M_DIM + N_DIM, 256, 0, stream>>>(x, q8, scl, azp, w, w8, adj);
    dim3 grid(N_DIM / 256, M_DIM / 256);
    gemm_kernel<<<grid, 512, 0, stream>>>(q8, w8, scl, azp, adj, wscale, bias, out);
}

// Round 6
// 461.170 us; speedup vs baseline: 1.3346x; 1.3346x over previous
//
#include <hip/hip_runtime.h>
#include <cstdint>
#include <cstddef>

// out[m,n] = scale[m]*wscale[n]*(sum_k q[m,k]*w8[n,k] - azp[m]*azp_adj[n]) + bias[n]
// M=8192, K=4096, N=4096. Exact int8 path.
//
// Round-6: FRAGMENT-TILED workspace layout + direct global->VGPR GEMM.
// Round 5 proved no-LDS free-running MFMA fails only because row-major
// fragments shatter into 16x64B transactions. Fix: prep kernels store
// A/B in MFMA-fragment tiles of 1 KiB:
//   addr(m, ko) = ((m>>4)*64 + (ko>>6))*1024 + (m&15)*64 + (ko&63)
// so a wave's fragment load (lane l: +r16*64 + quad*16) is one aligned
// contiguous 1 KiB block -> 8x128B coalesced transactions.

#define M_DIM 8192
#define K_DIM 4096
#define N_DIM 4096
#define NT 64   // K tiles of BK=64

typedef int v4i __attribute__((ext_vector_type(4)));

// ---------------------------------------------------------------------------
// Kernel 1 (fused): blocks [0, M) do per-token quant; blocks [M, M+N) do
// weight prep. Same math as the verified kernels; only the STORE ADDRESS of
// the packed int8 changes (fragment-tiled, see header).
// Thread t, iter i owns source bytes ko = 1024*i + 4*t .. +3 of its row, so
//   tile  = (m>>4)*64 + 16*i + (t>>4)
//   inner = (m&15)*16 + (t&15)            (int32 units)
// ---------------------------------------------------------------------------
__global__ __launch_bounds__(256) void prep_kernel(
    const float* __restrict__ x, signed char* __restrict__ q,
    float* __restrict__ scale_out, int* __restrict__ azp_out,
    const int* __restrict__ w, signed char* __restrict__ w8,
    int* __restrict__ azp_adj)
{
    const int t = threadIdx.x;
    if (blockIdx.x < M_DIM) {
        // ---- per-token asymmetric quantization, one block per row ----
        const int m = blockIdx.x;
        const float4* row4 = (const float4*)(x + (size_t)m * K_DIM);

        float4 v[4];
        float mx = -3.4e38f, mn = 3.4e38f;
#pragma unroll
        for (int i = 0; i < 4; ++i) {
            v[i] = row4[i * 256 + t];                  // coalesced
            mx = fmaxf(mx, fmaxf(fmaxf(v[i].x, v[i].y), fmaxf(v[i].z, v[i].w)));
            mn = fminf(mn, fminf(fminf(v[i].x, v[i].y), fminf(v[i].z, v[i].w)));
        }
#pragma unroll
        for (int off = 32; off; off >>= 1) {
            mx = fmaxf(mx, __shfl_down(mx, off));
            mn = fminf(mn, __shfl_down(mn, off));
        }
        __shared__ float smx[4], smn[4];
        if ((t & 63) == 0) { smx[t >> 6] = mx; smn[t >> 6] = mn; }
        __syncthreads();
        mx = fmaxf(fmaxf(smx[0], smx[1]), fmaxf(smx[2], smx[3]));
        mn = fminf(fminf(smn[0], smn[1]), fminf(smn[2], smn[3]));

        const float scale = (mx - mn) / 255.0f;
        const int azp = (int)rintf(-128.0f - mn / scale);
        if (t == 0) { scale_out[m] = scale; azp_out[m] = azp; }

        int* qt = (int*)q;
        const int mtile = (m >> 4) * 64;
        const int minner = (m & 15) * 16 + (t & 15);
        const float* vf = (const float*)v;
#pragma unroll
        for (int i = 0; i < 4; ++i) {
            int b[4];
#pragma unroll
            for (int j = 0; j < 4; ++j) {
                int qv = (int)rintf(vf[4 * i + j] / scale) + azp;
                qv = qv < -128 ? -128 : (qv > 127 ? 127 : qv);
                b[j] = qv;
            }
            const int pk =
                (b[0] & 255) | ((b[1] & 255) << 8) | ((b[2] & 255) << 16) | ((b[3] & 255) << 24);
            qt[(size_t)(mtile + 16 * i + (t >> 4)) * 256 + minner] = pk;
        }
    } else {
        // ---- weight prep: int32 [N,K] -> fragment-tiled int8 + col sums ----
        const int n = blockIdx.x - M_DIM;
        const int4* row = (const int4*)(w + (size_t)n * K_DIM);
        int* wt = (int*)w8;
        const int ntile = (n >> 4) * 64;
        const int ninner = (n & 15) * 16 + (t & 15);
        int sum = 0;
#pragma unroll
        for (int i = 0; i < 4; ++i) {
            int4 a = row[i * 256 + t];                 // coalesced
            sum += a.x + a.y + a.z + a.w;
            const int pk =
                (a.x & 255) | ((a.y & 255) << 8) | ((a.z & 255) << 16) | ((a.w & 255) << 24);
            wt[(size_t)(ntile + 16 * i + (t >> 4)) * 256 + ninner] = pk;
        }
#pragma unroll
        for (int off = 32; off; off >>= 1) sum += __shfl_down(sum, off);
        __shared__ int ssum[4];
        if ((t & 63) == 0) ssum[t >> 6] = sum;
        __syncthreads();
        if (t == 0) azp_adj[n] = ssum[0] + ssum[1] + ssum[2] + ssum[3];
    }
}

// ---------------------------------------------------------------------------
// Kernel 2: int8 GEMM, 256x256 block tile, BK=64, 8 waves (2M x 4N),
// per-wave 128x64 via mfma_i32_16x16x64_i8 -- NO LDS, NO BARRIERS.
// Fragment loads are direct global->VGPR from the tiled layout: one
// contiguous 1 KiB block per wave-load (lane offset r16*64 + quad*16).
// Per tile/CU: 96 coalesced loads (~768 cy L1-rate) vs MFMA 1306 cy;
// dependency-driven scheduling + 2 waves/SIMD overlap them (rounds 1/2/4
// proved the LDS lockstep made them SERIAL at ~3060 cy/tile).
//
// XCD rectangle map: dispatch i -> XCD i%8; each XCD's resident blocks
// form a 4m x 8n rectangle so per K-tile the XCD touches 4 A-tiles + 8
// B-tiles of 16 KiB = 192 KiB, L2-resident.
// ---------------------------------------------------------------------------
template<int RO>
__device__ __forceinline__ void mfma16(const v4i (&x)[4], const v4i (&y)[4], v4i (&acc)[8][4]) {
#pragma unroll
    for (int i = 0; i < 4; ++i)
#pragma unroll
        for (int j = 0; j < 4; ++j)
            acc[RO + i][j] = __builtin_amdgcn_mfma_i32_16x16x64_i8(x[i], y[j], acc[RO + i][j], 0, 0, 0);
}

__device__ __forceinline__ v4i ldg16(const signed char* p) {
    return *(const v4i*)p;
}

__global__ __launch_bounds__(512, 2) void gemm_kernel(
    const signed char* __restrict__ A,   // [M/16][K/64][16][64] tiled int8
    const signed char* __restrict__ B,   // [N/16][K/64][16][64] tiled int8
    const float* __restrict__ scale, const int* __restrict__ azp,
    const int* __restrict__ azp_adj, const float* __restrict__ wscale,
    const float* __restrict__ bias, float* __restrict__ out)
{
    const int t = threadIdx.x;
    const int lane = t & 63;
    const int wave = t >> 6;
    const int quad = lane >> 4;
    const int r16 = lane & 15;

    // XCD rectangle swizzle (see header comment)
    const int i = blockIdx.y * gridDim.x + blockIdx.x;    // 0..511
    const int r = i & 7, s = (i >> 3) & 31, rnd = i >> 8;
    const int bm = (16 * rnd + 4 * (r >> 1) + (s >> 3)) << 8;
    const int bn = (8 * (r & 1) + (s & 7)) << 8;

    const int wm = (wave >> 2) << 7;       // 0 or 128
    const int wn = (wave & 3) << 6;        // 0,64,128,192

    v4i acc[8][4];
#pragma unroll
    for (int ii = 0; ii < 8; ++ii)
#pragma unroll
        for (int j = 0; j < 4; ++j) acc[ii][j] = (v4i){0, 0, 0, 0};

    // fragment bases: tile stride 1024 B over kb, 65536 B over m/n-tile
    // index; lane offset r16*64 + quad*16 inside the 1 KiB fragment tile.
    const int laneoff = r16 * 64 + quad * 16;
    const signed char* aW = A + (size_t)((bm + wm) >> 4) * 65536 + laneoff;
    const signed char* bW = B + (size_t)((bn + wn) >> 4) * 65536 + laneoff;

    v4i afP[4], bfP[4], afQ[4], bfQ[4], ah[4];

    // prologue: tile 0 af/bf into set P
#pragma unroll
    for (int f = 0; f < 4; ++f) {
        afP[f] = ldg16(aW + f * 65536);
        bfP[f] = ldg16(bW + f * 65536);
    }

    for (int kt = 0; kt < NT; kt += 2) {
        const int k0 = kt << 10;             // kt*1024
        // ---- tile kt (set P) ----
#pragma unroll
        for (int f = 0; f < 4; ++f)
            ah[f] = ldg16(aW + (4 + f) * 65536 + k0);
#pragma unroll
        for (int f = 0; f < 4; ++f) {
            afQ[f] = ldg16(aW + f * 65536 + k0 + 1024);
            bfQ[f] = ldg16(bW + f * 65536 + k0 + 1024);
        }
        mfma16<0>(afP, bfP, acc);
        mfma16<4>(ah, bfP, acc);

        // ---- tile kt+1 (set Q) ----
#pragma unroll
        for (int f = 0; f < 4; ++f)
            ah[f] = ldg16(aW + (4 + f) * 65536 + k0 + 1024);
        if (kt + 2 < NT) {
#pragma unroll
            for (int f = 0; f < 4; ++f) {
                afP[f] = ldg16(aW + f * 65536 + k0 + 2048);
                bfP[f] = ldg16(bW + f * 65536 + k0 + 2048);
            }
        }
        mfma16<0>(afQ, bfQ, acc);
        mfma16<4>(ah, bfQ, acc);
    }

    // epilogue: out = scale[m]*wscale[n]*(acc - azp[m]*adj[n]) + bias[n]
#pragma unroll
    for (int ii = 0; ii < 8; ++ii) {
        const int mbase = bm + wm + ii * 16 + quad * 4;
        float sm[4]; int am[4];
#pragma unroll
        for (int rr = 0; rr < 4; ++rr) { sm[rr] = scale[mbase + rr]; am[rr] = azp[mbase + rr]; }
#pragma unroll
        for (int j = 0; j < 4; ++j) {
            const int n = bn + wn + j * 16 + r16;
            const float wsn = wscale[n];
            const int adjn = azp_adj[n];
            const float bn_ = bias[n];
#pragma unroll
            for (int rr = 0; rr < 4; ++rr) {
                const int c = acc[ii][j][rr] - am[rr] * adjn;
                out[(size_t)(mbase + rr) * N_DIM + n] = sm[rr] * wsn * (float)c + bn_;
            }
        }
    }
}

// ---------------------------------------------------------------------------
extern "C" void kernel_launch(void* const* d_in, const int* in_sizes, int n_in,
                              void* d_out, int out_size, void* d_ws, size_t ws_size,
                              hipStream_t stream) {
    const float* x      = (const float*)d_in[0];
    const int*   w      = (const int*)d_in[1];
    const float* wscale = (const float*)d_in[2];
    const float* bias   = (const float*)d_in[3];
    float* out = (float*)d_out;

    char* ws = (char*)d_ws;
    signed char* q8  = (signed char*)ws;                         // 32 MiB (tiled)
    signed char* w8  = (signed char*)(ws + 33554432);            // 16 MiB (tiled)
    float* scl       = (float*)(ws + 50331648);                  // 32 KiB
    int*   azp       = (int*)(ws + 50331648 + 32768);            // 32 KiB
    int*   adj       = (int*)(ws + 50331648 + 65536);            // 16 KiB

    prep_kernel<<<M_DIM + N_DIM, 256, 0, stream>>>(x, q8, scl, azp, w, w8, adj);
    dim3 grid(N_DIM / 256, M_DIM / 256);
    gemm_kernel<<<grid, 512, 0, stream>>>(q8, w8, scl, azp, adj, wscale, bias, out);
}

// Round 7
// 395.803 us; speedup vs baseline: 1.5550x; 1.1651x over previous
//
#include <hip/hip_runtime.h>
#include <cstdint>
#include <cstddef>

// out[m,n] = scale[m]*wscale[n]*(sum_k q[m,k]*w8[n,k] - azp[m]*azp_adj[n]) + bias[n]
// M=8192, K=4096, N=4096. Exact int8 path.

#define M_DIM 8192
#define K_DIM 4096
#define N_DIM 4096
#define NT 64   // K tiles of BK=64

typedef int v4i __attribute__((ext_vector_type(4)));

// ---------------------------------------------------------------------------
// Kernel 1 (fused): blocks [0, M) do per-token quant; blocks [M, M+N) do
// weight prep. Bit-identical math to the verified standalone kernels.
// Row-major q8/w8 stores (the LDS gemm's staging wants row-major).
// ---------------------------------------------------------------------------
__global__ __launch_bounds__(256) void prep_kernel(
    const float* __restrict__ x, signed char* __restrict__ q,
    float* __restrict__ scale_out, int* __restrict__ azp_out,
    const int* __restrict__ w, signed char* __restrict__ w8,
    int* __restrict__ azp_adj)
{
    const int t = threadIdx.x;
    if (blockIdx.x < M_DIM) {
        // ---- per-token asymmetric quantization, one block per row ----
        const int m = blockIdx.x;
        const float4* row4 = (const float4*)(x + (size_t)m * K_DIM);

        float4 v[4];
        float mx = -3.4e38f, mn = 3.4e38f;
#pragma unroll
        for (int i = 0; i < 4; ++i) {
            v[i] = row4[i * 256 + t];                  // coalesced
            mx = fmaxf(mx, fmaxf(fmaxf(v[i].x, v[i].y), fmaxf(v[i].z, v[i].w)));
            mn = fminf(mn, fminf(fminf(v[i].x, v[i].y), fminf(v[i].z, v[i].w)));
        }
#pragma unroll
        for (int off = 32; off; off >>= 1) {
            mx = fmaxf(mx, __shfl_down(mx, off));
            mn = fminf(mn, __shfl_down(mn, off));
        }
        __shared__ float smx[4], smn[4];
        if ((t & 63) == 0) { smx[t >> 6] = mx; smn[t >> 6] = mn; }
        __syncthreads();
        mx = fmaxf(fmaxf(smx[0], smx[1]), fmaxf(smx[2], smx[3]));
        mn = fminf(fminf(smn[0], smn[1]), fminf(smn[2], smn[3]));

        const float scale = (mx - mn) / 255.0f;
        const int azp = (int)rintf(-128.0f - mn / scale);
        if (t == 0) { scale_out[m] = scale; azp_out[m] = azp; }

        int* qrow = (int*)(q + (size_t)m * K_DIM);
        const float* vf = (const float*)v;
#pragma unroll
        for (int i = 0; i < 4; ++i) {
            int b[4];
#pragma unroll
            for (int j = 0; j < 4; ++j) {
                int qv = (int)rintf(vf[4 * i + j] / scale) + azp;
                qv = qv < -128 ? -128 : (qv > 127 ? 127 : qv);
                b[j] = qv;
            }
            qrow[i * 256 + t] =
                (b[0] & 255) | ((b[1] & 255) << 8) | ((b[2] & 255) << 16) | ((b[3] & 255) << 24);
        }
    } else {
        // ---- weight prep: int32 [N,K] -> int8 [N,K] + column sums ----
        const int n = blockIdx.x - M_DIM;
        const int4* row = (const int4*)(w + (size_t)n * K_DIM);
        int* w8row = (int*)(w8 + (size_t)n * K_DIM);
        int sum = 0;
#pragma unroll
        for (int i = 0; i < 4; ++i) {
            int4 a = row[i * 256 + t];                 // coalesced
            sum += a.x + a.y + a.z + a.w;
            w8row[i * 256 + t] =
                (a.x & 255) | ((a.y & 255) << 8) | ((a.z & 255) << 16) | ((a.w & 255) << 24);
        }
#pragma unroll
        for (int off = 32; off; off >>= 1) sum += __shfl_down(sum, off);
        __shared__ int ssum[4];
        if ((t & 63) == 0) ssum[t >> 6] = sum;
        __syncthreads();
        if (t == 0) azp_adj[n] = ssum[0] + ssum[1] + ssum[2] + ssum[3];
    }
}

// ---------------------------------------------------------------------------
// Kernel 2: int8 GEMM, 256x256 tile, BK=64, 8 waves (2M x 4N), per-wave
// 128x64 via mfma_i32_16x16x64_i8.
//
// Round-7: round-1's memory engine (ring-4 LDS, prefetch-3, stage-after-
// reads, counted vmcnt(8) -- never drains) with ONE barrier-pair and ONE
// lgkm stall per K-tile (round 1 had two of each; per-tile sync overhead
// was ~1350 cy against only 1306 cy of MFMA -- i8 has half the MFMA per
// tile that the bf16 m201 template amortizes the same overhead over).
//
// Per tile: { 12 ds_read_b128 (af,bf,ah); stage(kt+3) 4 gloads; s_barrier;
//            lgkmcnt(0); sched_barrier; setprio(1); 32 MFMA; setprio(0);
//            vmcnt(8); s_barrier }
//
// Hazard audit:
//  - reads(kt): buf kt&3 sealed by vmcnt(8) (retires stage(kt), issued at
//    tile kt-3) + barrier at end of tile kt-1.
//  - stage(kt+3) writes buf (kt-1)&3: every wave's reads of tile kt-1
//    retired at its lgkm0(kt-1), which precedes bar#2(kt-1), which precedes
//    any wave's stage(kt+3) issue.
//  - sched_barrier(0) after lgkm0 per rule 18 (hipcc hoists register-only
//    MFMA past inline-asm waitcnt otherwise).
//  - differs from failed round 2 in: stages AFTER reads, {bar; lgkm0; MFMA}
//    discipline kept, trailing barrier kept.
//  - XOR swizzle byte-identical to the proven kernel (0 conflicts measured):
//    LDS granule (row,c) holds global (row, c ^ ((row>>1)&3)); staging
//    pre-swizzles the GLOBAL address (LDS dst linear, mandatory for
//    global_load_lds); read swizzle collapses to quad ^ ((r16>>1)&3).
//  - XCD-aware bijective block swizzle (512 blocks, 512 % 8 == 0).
//  - __launch_bounds__(512,2): (512,4) spilled acc (round 3). Never again.
// ---------------------------------------------------------------------------
__device__ __forceinline__ void async_copy16(const signed char* g, signed char* l) {
    __builtin_amdgcn_global_load_lds(
        (const __attribute__((address_space(1))) void*)g,
        (__attribute__((address_space(3))) void*)l, 16, 0, 0);
}

template<int RO>
__device__ __forceinline__ void mfma16(const v4i (&x)[4], const v4i (&y)[4], v4i (&acc)[8][4]) {
#pragma unroll
    for (int i = 0; i < 4; ++i)
#pragma unroll
        for (int j = 0; j < 4; ++j)
            acc[RO + i][j] = __builtin_amdgcn_mfma_i32_16x16x64_i8(x[i], y[j], acc[RO + i][j], 0, 0, 0);
}

template<int CUR, bool STG, int VMN>
__device__ __forceinline__ void tile_body(
    int kt, signed char (*sA)[16384], signed char (*sB)[16384],
    const signed char* ag0, const signed char* ag1,
    const signed char* bg0, const signed char* bg1,
    int t, int aIdx, int bIdx, v4i (&acc)[8][4])
{
    const v4i* a4 = (const v4i*)&sA[CUR][0];
    const v4i* b4 = (const v4i*)&sB[CUR][0];

    // all 12 fragment reads for this tile
    v4i af[4], bf[4], ah[4];
#pragma unroll
    for (int i = 0; i < 4; ++i) {
        af[i] = a4[aIdx + i * 64];           // rows wm      + i*16 + r16
        bf[i] = b4[bIdx + i * 64];           // rows wn      + i*16 + r16
    }
#pragma unroll
    for (int i = 0; i < 4; ++i)
        ah[i] = a4[aIdx + 256 + i * 64];     // rows wm + 64 + i*16 + r16

    // stage tile kt+3 into buf (kt-1)&3 (fully consumed; sealed by the
    // lgkm0->bar#2 chain of tile kt-1)
    if constexpr (STG) {
        const int ko = (kt + 3) << 6;
        signed char* dA = &sA[(CUR + 3) & 3][0];
        signed char* dB = &sB[(CUR + 3) & 3][0];
        async_copy16(ag0 + ko, dA + t * 16);
        async_copy16(ag1 + ko, dA + 8192 + t * 16);
        async_copy16(bg0 + ko, dB + t * 16);
        async_copy16(bg1 + ko, dB + 8192 + t * 16);
    }

    asm volatile("s_barrier" ::: "memory");
    asm volatile("s_waitcnt lgkmcnt(0)" ::: "memory");
    __builtin_amdgcn_sched_barrier(0);
    __builtin_amdgcn_s_setprio(1);
    mfma16<0>(af, bf, acc);
    mfma16<4>(ah, bf, acc);
    __builtin_amdgcn_s_setprio(0);

    // seal tile kt+1 for everyone (counted: 8 newer stage-loads remain)
    if constexpr (VMN == 8)      asm volatile("s_waitcnt vmcnt(8)" ::: "memory");
    else if constexpr (VMN == 4) asm volatile("s_waitcnt vmcnt(4)" ::: "memory");
    else if constexpr (VMN == 0) asm volatile("s_waitcnt vmcnt(0)" ::: "memory");
    if constexpr (VMN >= 0)
        asm volatile("s_barrier" ::: "memory");
}

__global__ __launch_bounds__(512, 2) void gemm_kernel(
    const signed char* __restrict__ A,   // [M,K] quantized activations
    const signed char* __restrict__ B,   // [N,K] int8 weights
    const float* __restrict__ scale, const int* __restrict__ azp,
    const int* __restrict__ azp_adj, const float* __restrict__ wscale,
    const float* __restrict__ bias, float* __restrict__ out)
{
    __shared__ signed char sA[4][16384];   // 4-deep ring x 256 rows x 64B
    __shared__ signed char sB[4][16384];   // total 128 KiB, 1 block/CU

    const int t = threadIdx.x;
    const int lane = t & 63;
    const int wave = t >> 6;
    const int quad = lane >> 4;
    const int r16 = lane & 15;

    // XCD-aware swizzle over the 512 blocks (bijective since 512 % 8 == 0)
    int bid = blockIdx.y * gridDim.x + blockIdx.x;
    bid = (bid & 7) * 64 + (bid >> 3);
    const int bn = (bid & 15) << 8;        // 16 n-blocks
    const int bm = (bid >> 4) << 8;        // 32 m-blocks

    const int wm = (wave >> 2) << 7;       // 0 or 128
    const int wn = (wave & 3) << 6;        // 0,64,128,192

    v4i acc[8][4];
#pragma unroll
    for (int i = 0; i < 8; ++i)
#pragma unroll
        for (int j = 0; j < 4; ++j) acc[i][j] = (v4i){0, 0, 0, 0};

    // staging: thread t fills LDS granule t of a 128-row chunk (row = t>>2,
    // colL = t&3); global col = colL ^ ((row>>1)&3) = (t&3) ^ ((t>>3)&3).
    const int srow = t >> 2;                               // 0..127
    const int scol = ((t & 3) ^ ((t >> 3) & 3)) << 4;      // pre-swizzled global col
    const signed char* ag0 = A + (size_t)(bm + srow) * K_DIM + scol;
    const signed char* ag1 = A + (size_t)(bm + 128 + srow) * K_DIM + scol;
    const signed char* bg0 = B + (size_t)(bn + srow) * K_DIM + scol;
    const signed char* bg1 = B + (size_t)(bn + 128 + srow) * K_DIM + scol;

#define STAGE_A(kt) do { const int _b = (kt) & 3; const int _ko = (kt) << 6; \
    async_copy16(ag0 + _ko, &sA[_b][t * 16]); \
    async_copy16(ag1 + _ko, &sA[_b][8192 + t * 16]); } while (0)
#define STAGE_B(kt) do { const int _b = (kt) & 3; const int _ko = (kt) << 6; \
    async_copy16(bg0 + _ko, &sB[_b][t * 16]); \
    async_copy16(bg1 + _ko, &sB[_b][8192 + t * 16]); } while (0)

    // per-lane LDS read indices (v4i granule units); swizzle collapses to a
    // per-lane constant since wm/wn/i*16 are 0 mod 8.
    const int swz = quad ^ ((r16 >> 1) & 3);
    const int aIdx = (wm + r16) * 4 + swz;   // granule index within one buffer
    const int bIdx = (wn + r16) * 4 + swz;

    // prologue: fill tiles 0,1,2 (12 loads/wave in flight), seal tile 0
    STAGE_A(0); STAGE_B(0);
    STAGE_A(1); STAGE_B(1);
    STAGE_A(2); STAGE_B(2);
    asm volatile("s_waitcnt vmcnt(8)" ::: "memory");
    asm volatile("s_barrier" ::: "memory");

    // main loop: 4-tile unroll keeps ring indices compile-time (rule 20)
    for (int kt = 0; kt < NT - 4; kt += 4) {
        tile_body<0, true, 8>(kt,     sA, sB, ag0, ag1, bg0, bg1, t, aIdx, bIdx, acc);
        tile_body<1, true, 8>(kt + 1, sA, sB, ag0, ag1, bg0, bg1, t, aIdx, bIdx, acc);
        tile_body<2, true, 8>(kt + 2, sA, sB, ag0, ag1, bg0, bg1, t, aIdx, bIdx, acc);
        tile_body<3, true, 8>(kt + 3, sA, sB, ag0, ag1, bg0, bg1, t, aIdx, bIdx, acc);
    }
    // peeled tail: tiles 60..63 (last stage at tile 60 -> tile 63)
    tile_body<0, true,  8>(NT - 4, sA, sB, ag0, ag1, bg0, bg1, t, aIdx, bIdx, acc);
    tile_body<1, false, 4>(NT - 3, sA, sB, ag0, ag1, bg0, bg1, t, aIdx, bIdx, acc);
    tile_body<2, false, 0>(NT - 2, sA, sB, ag0, ag1, bg0, bg1, t, aIdx, bIdx, acc);
    tile_body<3, false, -1>(NT - 1, sA, sB, ag0, ag1, bg0, bg1, t, aIdx, bIdx, acc);

#undef STAGE_A
#undef STAGE_B

    // epilogue: out = scale[m]*wscale[n]*(acc - azp[m]*adj[n]) + bias[n]
#pragma unroll
    for (int i = 0; i < 8; ++i) {
        const int mbase = bm + wm + i * 16 + quad * 4;
        float sm[4]; int am[4];
#pragma unroll
        for (int r = 0; r < 4; ++r) { sm[r] = scale[mbase + r]; am[r] = azp[mbase + r]; }
#pragma unroll
        for (int j = 0; j < 4; ++j) {
            const int n = bn + wn + j * 16 + r16;
            const float wsn = wscale[n];
            const int adjn = azp_adj[n];
            const float bn_ = bias[n];
#pragma unroll
            for (int r = 0; r < 4; ++r) {
                const int c = acc[i][j][r] - am[r] * adjn;
                out[(size_t)(mbase + r) * N_DIM + n] = sm[r] * wsn * (float)c + bn_;
            }
        }
    }
}

// ---------------------------------------------------------------------------
extern "C" void kernel_launch(void* const* d_in, const int* in_sizes, int n_in,
                              void* d_out, int out_size, void* d_ws, size_t ws_size,
                              hipStream_t stream) {
    const float* x      = (const float*)d_in[0];
    const int*   w      = (const int*)d_in[1];
    const float* wscale = (const float*)d_in[2];
    const float* bias   = (const float*)d_in[3];
    float* out = (float*)d_out;

    char* ws = (char*)d_ws;
    signed char* q8  = (signed char*)ws;                         // 32 MiB
    signed char* w8  = (signed char*)(ws + 33554432);            // 16 MiB
    float* scl       = (float*)(ws + 50331648);                  // 32 KiB
    int*   azp       = (int*)(ws + 50331648 + 32768);            // 32 KiB
    int*   adj       = (int*)(ws + 50331648 + 65536);            // 16 KiB

    prep_kernel<<<M_DIM + N_DIM, 256, 0, stream>>>(x, q8, scl, azp, w, w8, adj);
    dim3 grid(N_DIM / 256, M_DIM / 256);
    gemm_kernel<<<grid, 512, 0, stream>>>(q8, w8, scl, azp, adj, wscale, bias, out);
}